// Round 5
// baseline (197.958 us; speedup 1.0000x reference)
//
#include <hip/hip_runtime.h>

#define HH 128
#define WW 128
#define CC 96
#define KK 7

// Deep-prefetch streaming morphological dilation (7x7 max-plus, zero-pad,
// ReLU folded). Diagnosis: all prior variants were outstanding-load-limited
// (Little's law: ~0.3 loads in flight per wave -> 2.4 TB/s, exactly measured).
// Fix: phase A issues ALL 42 dwordx4 loads (14 row strips) back-to-back with
// no dependent selects (edge handling moved to address selection, computed
// once); sched_barrier pins the boundary; phase B applies zero-selects and
// the max3 streaming core. launch_bounds(256,2) grants ~220 VGPRs.
//
// Block: 256 threads = 32 col-groups x 8 row-groups; one (b,c) plane half.
// Thread: 4 cols x 8 out rows; weight row i = s - yl folds statically.

__device__ __forceinline__ float max3f(float a, float b, float c) {
  float r;
  asm("v_max3_f32 %0, %1, %2, %3" : "=v"(r) : "v"(a), "v"(b), "v"(c));
  return r;
}

__global__ __launch_bounds__(256, 2) void morph_kernel(
    const float* __restrict__ x, const float* __restrict__ weight,
    float* __restrict__ out) {
  const int t = threadIdx.x;
  const int cg = t & 31;   // col group 0..31
  const int rg = t >> 5;   // row group 0..7
  const int half = blockIdx.x & 1;
  const int plane = blockIdx.x >> 1;  // b*CC + c
  const int c = plane % CC;

  const float* __restrict__ xp = x + (size_t)plane * (HH * WW);
  float* __restrict__ op = out + (size_t)plane * (HH * WW);
  const float* __restrict__ Wc = weight + c * (KK * KK);

  // Preload 49 channel weights; force into SGPRs (block-uniform).
  float wv[KK * KK];
#pragma unroll
  for (int k = 0; k < KK * KK; ++k)
    wv[k] = __int_as_float(__builtin_amdgcn_readfirstlane(__float_as_int(Wc[k])));

  const int tc0 = cg << 2;              // first out col of this thread
  const int row0 = half * 64 + rg * 8;  // first out row of this thread
  const bool lok = (tc0 >= 4);
  const bool rok = (tc0 <= WW - 8);

  // ---- Phase A: issue all 42 loads raw (no value selects). ----
  // Edge lanes (cg==0 / cg==31) would read 16B out of plane; redirect their
  // A/C base to the always-valid middle strip (one 64-bit cndmask per base,
  // computed BEFORE any load -> loads have no data dependencies).
  const float* pb = xp + (row0 - 3) * WW + (tc0 - 4);  // strip 0, col tc0-4
  const float* pA0 = lok ? pb : pb + 4;
  const float* pB0 = pb + 4;
  const float* pC0 = rok ? pb + 8 : pb + 4;

  float4 A[14], B[14], C[14];
#pragma unroll
  for (int s = 0; s < 14; ++s) {
    if (s < 3 || s >= 11) {
      // Only first/last 3 strips can be out of plane vertically.
      const int r = row0 - 3 + s;
      if ((unsigned)r < (unsigned)HH) {
        A[s] = *(const float4*)(pA0 + s * WW);
        B[s] = *(const float4*)(pB0 + s * WW);
        C[s] = *(const float4*)(pC0 + s * WW);
      } else {
        A[s] = make_float4(0.f, 0.f, 0.f, 0.f);
        B[s] = make_float4(0.f, 0.f, 0.f, 0.f);
        C[s] = make_float4(0.f, 0.f, 0.f, 0.f);
      }
    } else {
      A[s] = *(const float4*)(pA0 + s * WW);
      B[s] = *(const float4*)(pB0 + s * WW);
      C[s] = *(const float4*)(pC0 + s * WW);
    }
  }
  // Pin: no load may sink into the compute phase.
  __builtin_amdgcn_sched_barrier(0);

  // ---- Phase B: streaming accumulate (ReLU folded: acc starts at 0). ----
  float acc[8][4];
#pragma unroll
  for (int y = 0; y < 8; ++y)
#pragma unroll
    for (int q = 0; q < 4; ++q) acc[y][q] = 0.f;

#pragma unroll
  for (int s = 0; s < 14; ++s) {
    // Assemble 10-wide strip (cols tc0-3 .. tc0+6); zero-select edges here.
    float d1 = lok ? A[s].y : 0.f;
    float d2 = lok ? A[s].z : 0.f;
    float d3 = lok ? A[s].w : 0.f;
    float d4 = B[s].x, d5 = B[s].y, d6 = B[s].z, d7 = B[s].w;
    float d8 = rok ? C[s].x : 0.f;
    float d9 = rok ? C[s].y : 0.f;
    float d10 = rok ? C[s].z : 0.f;
    const float dd[10] = {d1, d2, d3, d4, d5, d6, d7, d8, d9, d10};

#pragma unroll
    for (int yl = 0; yl < 8; ++yl) {
      const int i = s - yl;            // weight row; folds at compile time
      if (i < 0 || i >= KK) continue;  // static guard (full unroll)
      const float w0 = wv[i * 7 + 0], w1 = wv[i * 7 + 1], w2 = wv[i * 7 + 2],
                  w3 = wv[i * 7 + 3], w4 = wv[i * 7 + 4], w5 = wv[i * 7 + 5],
                  w6 = wv[i * 7 + 6];
#pragma unroll
      for (int q = 0; q < 4; ++q) {
        const float t0 = dd[q + 0] + w0;
        const float t1 = dd[q + 1] + w1;
        const float t2 = dd[q + 2] + w2;
        const float t3 = dd[q + 3] + w3;
        const float t4 = dd[q + 4] + w4;
        const float t5 = dd[q + 5] + w5;
        const float t6 = dd[q + 6] + w6;
        const float u = max3f(t0, t1, t2);
        const float v = max3f(t3, t4, t5);
        const float m = max3f(u, v, t6);
        acc[yl][q] = fmaxf(acc[yl][q], m);
      }
    }

    // Output row (row0 + s - 6) got its last contribution this iteration.
    if (s >= 6) {
      const int yl = s - 6;
      float4 o = make_float4(acc[yl][0], acc[yl][1], acc[yl][2], acc[yl][3]);
      *(float4*)(op + (size_t)(row0 + yl) * WW + tc0) = o;
    }
  }
}

extern "C" void kernel_launch(void* const* d_in, const int* in_sizes, int n_in,
                              void* d_out, int out_size, void* d_ws, size_t ws_size,
                              hipStream_t stream) {
  const float* x = (const float*)d_in[0];
  const float* w = (const float*)d_in[1];
  float* out = (float*)d_out;
  // 16 batches * 96 channels * 2 half-planes
  const int nblocks = 16 * CC * 2;
  morph_kernel<<<nblocks, 256, 0, stream>>>(x, w, out);
}

// Round 6
// 188.081 us; speedup vs baseline: 1.0525x; 1.0525x over previous
//
#include <hip/hip_runtime.h>

#define HH 128
#define WW 128
#define CC 96
#define KK 7

// Streaming morphological dilation (7x7 max-plus, zero-pad, ReLU folded)
// with software-pipelined loads at prefetch distance 2.
//
// Diagnosis history: R0/R1/R4 (distance-0 JIT loads) all ~76-79us with ~25us
// true VALU issue -> ~50us exposed global-load latency per wave (compiler at
// 52-56 VGPR keeps ~1 strip in flight; 14 strips x ~900cyc / ~3 waves-SIMD
// coverage ~= measured). R5 (distance-14) collapsed: 168 live values forced
// AGPR shuffling, occupancy 20%, 105us. This round: distance 2 (6 loads in
// flight, ~90 VGPR), rolling 3-strip buffer, static %3 indexing under full
// unroll, launch_bounds(256,4) to grant the registers.
//
// Block: 256 threads = 32 col-groups x 8 row-groups; one (b,c) plane half
// (64 rows x 128 cols). Thread: 4 cols x 8 out rows; weight row i = s - yl
// folds statically. fmaxf chains fuse to v_max3_f32 (verified: explicit asm
// max3 in R4 was exactly null).

__device__ __forceinline__ void load_row(float* d, const float* __restrict__ xp,
                                         int r, int tc0, bool lok, bool rok) {
  if ((unsigned)r < (unsigned)HH) {
    const float* p = xp + r * WW + tc0 - 4;
    float4 a, b, c;
    if (lok) a = *(const float4*)(p);
    else     a = make_float4(0.f, 0.f, 0.f, 0.f);
    b = *(const float4*)(p + 4);
    if (rok) c = *(const float4*)(p + 8);
    else     c = make_float4(0.f, 0.f, 0.f, 0.f);
    d[0] = a.x; d[1] = a.y; d[2] = a.z; d[3] = a.w;
    d[4] = b.x; d[5] = b.y; d[6] = b.z; d[7] = b.w;
    d[8] = c.x; d[9] = c.y; d[10] = c.z; d[11] = c.w;
  } else {
#pragma unroll
    for (int i = 0; i < 12; ++i) d[i] = 0.f;
  }
}

__global__ __launch_bounds__(256, 4) void morph_kernel(
    const float* __restrict__ x, const float* __restrict__ weight,
    float* __restrict__ out) {
  const int t = threadIdx.x;
  const int cg = t & 31;   // col group 0..31
  const int rg = t >> 5;   // row group 0..7
  const int half = blockIdx.x & 1;
  const int plane = blockIdx.x >> 1;  // b*CC + c
  const int c = plane % CC;

  const float* __restrict__ xp = x + (size_t)plane * (HH * WW);
  float* __restrict__ op = out + (size_t)plane * (HH * WW);
  const float* __restrict__ Wc = weight + c * (KK * KK);

  // Preload 49 channel weights; force into SGPRs (block-uniform).
  float wv[KK * KK];
#pragma unroll
  for (int k = 0; k < KK * KK; ++k)
    wv[k] = __int_as_float(__builtin_amdgcn_readfirstlane(__float_as_int(Wc[k])));

  const int tc0 = cg << 2;              // first out col of this thread
  const int row0 = half * 64 + rg * 8;  // first out row of this thread
  const bool lok = (tc0 >= 4);
  const bool rok = (tc0 <= WW - 8);

  // Pending output accumulators. ReLU folded in: start at 0 (= max(0, .)).
  float acc[8][4];
#pragma unroll
  for (int y = 0; y < 8; ++y)
#pragma unroll
    for (int q = 0; q < 4; ++q) acc[y][q] = 0.f;

  // Rolling 3-strip buffer; statically indexed under full unroll.
  float dbuf[3][12];

  // Prologue: issue strips 0 and 1.
  load_row(dbuf[0], xp, row0 - 3 + 0, tc0, lok, rok);
  load_row(dbuf[1], xp, row0 - 3 + 1, tc0, lok, rok);

  // Stream input rows row0-3 .. row0+10 (14 strips for 8 output rows).
#pragma unroll
  for (int s = 0; s < 14; ++s) {
    // Prefetch strip s+2 before consuming strip s: its 3 loads plus strip
    // s+1's stay in flight; the use below only waits (counted vmcnt) for
    // strip s's registers.
    if (s + 2 < 14)
      load_row(dbuf[(s + 2) % 3], xp, row0 - 3 + (s + 2), tc0, lok, rok);

    const float* d = dbuf[s % 3];  // cols [tc0-4, tc0+8); used: d[1..10]

#pragma unroll
    for (int yl = 0; yl < 8; ++yl) {
      const int i = s - yl;            // weight row; folds at compile time
      if (i < 0 || i >= KK) continue;  // static guard (full unroll)
      const float w0 = wv[i * 7 + 0], w1 = wv[i * 7 + 1], w2 = wv[i * 7 + 2],
                  w3 = wv[i * 7 + 3], w4 = wv[i * 7 + 4], w5 = wv[i * 7 + 5],
                  w6 = wv[i * 7 + 6];
#pragma unroll
      for (int q = 0; q < 4; ++q) {
        const float t0 = d[q + 1] + w0;
        const float t1 = d[q + 2] + w1;
        const float t2 = d[q + 3] + w2;
        const float t3 = d[q + 4] + w3;
        const float t4 = d[q + 5] + w4;
        const float t5 = d[q + 6] + w5;
        const float t6 = d[q + 7] + w6;
        float m = acc[yl][q];
        m = fmaxf(fmaxf(m, t0), t1);   // fuses to v_max3_f32 (verified R4)
        m = fmaxf(fmaxf(m, t2), t3);
        m = fmaxf(fmaxf(m, t4), t5);
        m = fmaxf(m, t6);
        acc[yl][q] = m;
      }
    }

    // Output row (row0 + s - 6) got its last contribution this iteration.
    if (s >= 6) {
      const int yl = s - 6;
      float4 o = make_float4(acc[yl][0], acc[yl][1], acc[yl][2], acc[yl][3]);
      *(float4*)(op + (size_t)(row0 + yl) * WW + tc0) = o;
    }
  }
}

extern "C" void kernel_launch(void* const* d_in, const int* in_sizes, int n_in,
                              void* d_out, int out_size, void* d_ws, size_t ws_size,
                              hipStream_t stream) {
  const float* x = (const float*)d_in[0];
  const float* w = (const float*)d_in[1];
  float* out = (float*)d_out;
  // 16 batches * 96 channels * 2 half-planes
  const int nblocks = 16 * CC * 2;
  morph_kernel<<<nblocks, 256, 0, stream>>>(x, w, out);
}